// Round 6
// baseline (67.734 us; speedup 1.0000x reference)
//
#include <hip/hip_runtime.h>

#define LSEQ   2048
#define DDIM   1024
#define BR     32          // rows per WG (same row range for x1 and x2)
#define WPB    127         // per batch: 64 diagonal + 63 offset, interleaved D0,O0,D1,...
#define DECAY_F 0.8f

typedef __attribute__((ext_vector_type(8))) short  short8;
typedef __attribute__((ext_vector_type(4))) float  f32x4;

__device__ __forceinline__ unsigned short f2bf(float f) {
  unsigned u = __float_as_uint(f);
  u += 0x7fffu + ((u >> 16) & 1u);
  return (unsigned short)(u >> 16);
}

__device__ __forceinline__ short8 cvt8(f32x4 lo, f32x4 hi, float& nsq) {
  short8 v;
  #pragma unroll
  for (int j = 0; j < 4; ++j) { float x = lo[j]; nsq += x * x; v[j]     = (short)f2bf(x); }
  #pragma unroll
  for (int j = 0; j < 4; ++j) { float x = hi[j]; nsq += x * x; v[4 + j] = (short)f2bf(x); }
  return v;
}

__global__ __launch_bounds__(256, 4)
void tsp_energy_kernel(const float* __restrict__ x1,
                       const float* __restrict__ x2,
                       float* __restrict__ out) {
  // grid = 1016 = 8*127: bid&7 = batch = XCD (round-robin dispatch), bid>>3 = r.
  // D/O interleaved in dispatch order (r even -> D_m, r odd -> O_m) so blocks
  // sharing 16 rows are co-resident on the same XCD's L2.
  const int bid  = blockIdx.x;
  const int b    = bid & 7;
  const int r    = bid >> 3;               // 0..126
  const bool isO = (r & 1);
  const int m    = r >> 1;
  const int row0 = isO ? (m * BR + 16) : (m * BR);

  const int t    = threadIdx.x;
  const int lane = t & 63;
  const int wave = t >> 6;                 // 4 waves: (mrow, ncol) quadrants
  const int l15  = lane & 15;
  const int g4   = lane >> 4;
  const int mrow = (wave >> 1) * 16;
  const int ncol = (wave & 1) * 16;

  __shared__ float outAcc[BR][2];

  // direct-from-global MFMA fragments: lane covers row l15, k = g4*8..+7 (+32)
  const float* ap = x1 + ((size_t)b * LSEQ + row0 + mrow + l15) * DDIM + g4 * 8;
  const float* bp = x2 + ((size_t)b * LSEQ + row0 + ncol + l15) * DDIM + g4 * 8;

  float nsqa = 0.f, nsqb = 0.f;
  f32x4 acc = (f32x4){0.f, 0.f, 0.f, 0.f};

  // 2-deep named-register pipeline, one slot = one k64 block (8 x f32x4 loads)
  f32x4 A00, A01, A02, A03, B00, B01, B02, B03;
  f32x4 A10, A11, A12, A13, B10, B11, B12, B13;

#define LOAD0(blk) do { const float* _p = ap + (blk) * 64;                         \
    A00 = *(const f32x4*)(_p);      A01 = *(const f32x4*)(_p + 4);                 \
    A02 = *(const f32x4*)(_p + 32); A03 = *(const f32x4*)(_p + 36);                \
    const float* _q = bp + (blk) * 64;                                             \
    B00 = *(const f32x4*)(_q);      B01 = *(const f32x4*)(_q + 4);                 \
    B02 = *(const f32x4*)(_q + 32); B03 = *(const f32x4*)(_q + 36); } while (0)

#define LOAD1(blk) do { const float* _p = ap + (blk) * 64;                         \
    A10 = *(const f32x4*)(_p);      A11 = *(const f32x4*)(_p + 4);                 \
    A12 = *(const f32x4*)(_p + 32); A13 = *(const f32x4*)(_p + 36);                \
    const float* _q = bp + (blk) * 64;                                             \
    B10 = *(const f32x4*)(_q);      B11 = *(const f32x4*)(_q + 4);                 \
    B12 = *(const f32x4*)(_q + 32); B13 = *(const f32x4*)(_q + 36); } while (0)

#define PROC0(nextblk, donext) do {                                                \
    short8 af0 = cvt8(A00, A01, nsqa);                                             \
    short8 af1 = cvt8(A02, A03, nsqa);                                             \
    short8 bf0 = cvt8(B00, B01, nsqb);                                             \
    short8 bf1 = cvt8(B02, B03, nsqb);                                             \
    if (donext) LOAD0(nextblk);                                                    \
    acc = __builtin_amdgcn_mfma_f32_16x16x32_bf16(af0, bf0, acc, 0, 0, 0);         \
    acc = __builtin_amdgcn_mfma_f32_16x16x32_bf16(af1, bf1, acc, 0, 0, 0); } while (0)

#define PROC1(nextblk, donext) do {                                                \
    short8 af0 = cvt8(A10, A11, nsqa);                                             \
    short8 af1 = cvt8(A12, A13, nsqa);                                             \
    short8 bf0 = cvt8(B10, B11, nsqb);                                             \
    short8 bf1 = cvt8(B12, B13, nsqb);                                             \
    if (donext) LOAD1(nextblk);                                                    \
    acc = __builtin_amdgcn_mfma_f32_16x16x32_bf16(af0, bf0, acc, 0, 0, 0);         \
    acc = __builtin_amdgcn_mfma_f32_16x16x32_bf16(af1, bf1, acc, 0, 0, 0); } while (0)

  // ---- barrier-free K-loop: 16 k64 blocks, 2-deep prefetch ----
  LOAD0(0);
  LOAD1(1);
  #pragma unroll
  for (int it = 0; it < 8; ++it) {
    PROC0(2 * it + 2, it < 7);
    PROC1(2 * it + 3, it < 7);
  }

  // ---- norms: lane l covered k = {blk*64 + [0,32) ∩ (g4*8..+7 pattern)};
  // lanes {l15, l15+16, l15+32, l15+48} jointly cover full k for row l15.
  nsqa += __shfl_xor(nsqa, 16, 64);
  nsqa += __shfl_xor(nsqa, 32, 64);        // lane holds full |x1[row0+mrow+l15]|^2
  nsqb += __shfl_xor(nsqb, 16, 64);
  nsqb += __shfl_xor(nsqb, 32, 64);        // lane holds full |x2[row0+ncol+l15]|^2
  const float iv2 = 1.f / fmaxf(sqrtf(nsqb), 1e-8f);   // lane-local: col jc = ncol+l15
  const float nr1 = sqrtf(nsqa);

  // ---- epilogue: weight, normalize, reduce over this wave's 16 cols ----
  const int jc = ncol + l15;
  float rs[4];
  #pragma unroll
  for (int q = 0; q < 4; ++q) {
    const int ic = mrow + g4 * 4 + q;      // acc[q] -> C[row=g4*4+q][col=l15]
    float w = __expf(-DECAY_F * fabsf((float)(ic - jc)));
    if (isO && ((ic < 16) == (jc < 16))) w = 0.f;      // O: cross-boundary only
    const float n1 = __shfl(nr1, (lane & 48) | (g4 * 4 + q), 64);
    const float iv1 = 1.f / fmaxf(n1, 1e-8f);
    rs[q] = w * iv2 * iv1 * acc[q];
  }
  #pragma unroll
  for (int mm = 1; mm <= 8; mm <<= 1) {
    #pragma unroll
    for (int q = 0; q < 4; ++q) rs[q] += __shfl_xor(rs[q], mm, 64);
  }
  if (l15 == 0) {
    #pragma unroll
    for (int q = 0; q < 4; ++q) outAcc[mrow + g4 * 4 + q][wave & 1] = rs[q];
  }
  __syncthreads();

  if (t < BR) {
    const float v  = outAcc[t][0] + outAcc[t][1];      // inv1 already folded in
    const int gi   = row0 + t;
    float res;
    if (isO) {
      res = -v;
    } else {
      const float A  = __expf(-DECAY_F);
      const float a1 = __expf(-DECAY_F * (float)(gi + 1));
      const float a2 = __expf(-DECAY_F * (float)(LSEQ - gi));
      res = (1.f - a1 + A - a2) / (1.f - A) - v;       // exact sum_j a^|i-j|
    }
    atomicAdd(out + (size_t)b * LSEQ + gi, res);
  }
}

extern "C" void kernel_launch(void* const* d_in, const int* in_sizes, int n_in,
                              void* d_out, int out_size, void* d_ws, size_t ws_size,
                              hipStream_t stream) {
  const float* x1 = (const float*)d_in[0];
  const float* x2 = (const float*)d_in[1];
  float* out = (float*)d_out;
  hipMemsetAsync(d_out, 0, (size_t)out_size * sizeof(float), stream);
  dim3 grid(8 * WPB);   // 1016 WGs
  dim3 block(256);
  tsp_energy_kernel<<<grid, block, 0, stream>>>(x1, x2, out);
}

// Round 7
// 65.414 us; speedup vs baseline: 1.0355x; 1.0355x over previous
//
#include <hip/hip_runtime.h>

#define LSEQ   2048
#define DDIM   1024
#define TI     32           // output rows per WG
#define TJ     64           // x2 window rows (halo 16 each side)
#define NROW   (TI + TJ)    // 96 staged rows per chunk
#define BK     64
#define NCH    (DDIM / BK)  // 16
#define LDST   72           // 64 + 8 pad bf16 elems -> 144B row stride
#define DECAY_F 0.8f

typedef __attribute__((ext_vector_type(8))) short  short8;
typedef __attribute__((ext_vector_type(4))) float  f32x4;

__device__ __forceinline__ unsigned short f2bf(float f) {
  unsigned u = __float_as_uint(f);
  u += 0x7fffu + ((u >> 16) & 1u);
  return (unsigned short)(u >> 16);
}

__device__ __forceinline__ void cvt_store(unsigned short* dst, f32x4 lo, f32x4 hi, float& nsq) {
  short8 v;
  #pragma unroll
  for (int j = 0; j < 4; ++j) { float x = lo[j]; nsq += x * x; v[j]     = (short)f2bf(x); }
  #pragma unroll
  for (int j = 0; j < 4; ++j) { float x = hi[j]; nsq += x * x; v[4 + j] = (short)f2bf(x); }
  *(short8*)dst = v;
}

__global__ __launch_bounds__(256, 2)
void tsp_energy_kernel(const float* __restrict__ x1,
                       const float* __restrict__ x2,
                       float* __restrict__ out) {
  // grid = 512 = 8 XCDs x 64: bid&7 = XCD = batch, bid>>3 = i-tile index.
  // Consecutive i-tiles (32-row halo overlap in x2) are XCD-local -> L2 hits.
  const int bid = blockIdx.x;
  const int b   = bid & 7;
  const int i0  = (bid >> 3) * TI;

  const int t    = threadIdx.x;
  const int lane = t & 63;
  const int wave = t >> 6;            // 4 waves: (mrow 0/16) x (ncol 0/32)
  const int l15  = lane & 15;
  const int g4   = lane >> 4;
  const int mrow = (wave >> 1) * 16;
  const int ncol = (wave & 1) * 32;

  __shared__ unsigned short T[2][NROW][LDST];   // rows 0-31 = x1, 32-95 = x2 window
  __shared__ float invA[TI], invB[TJ];
  __shared__ float outAcc[TI][2];

  // staging: seg s (0..2) -> tile row s*32 + (t>>3), cols (t&7)*8 .. +7
  const int srow = t >> 3;            // 0..31
  const int scol = (t & 7) * 8;
  const int jr1  = i0 - 16 + srow;    // seg1 global x2 row
  const int jr2  = i0 + 16 + srow;    // seg2 global x2 row
  const bool ok1 = (jr1 >= 0);
  const bool ok2 = (jr2 < LSEQ);

  const float* p0 = x1 + ((size_t)b * LSEQ + i0 + srow) * DDIM + scol;
  const float* p1 = x2 + ((size_t)b * LSEQ + (ok1 ? jr1 : 0)) * DDIM + scol;
  const float* p2 = x2 + ((size_t)b * LSEQ + (ok2 ? jr2 : 0)) * DDIM + scol;
  unsigned short* lbase = &T[0][srow][scol];
  const int BUFE = NROW * LDST;       // elems per buffer
  const int SEGE = 32 * LDST;         // elems per 32-row seg

  float n0 = 0.f, n1 = 0.f, n2 = 0.f;
  f32x4 acc0 = (f32x4){0.f,0.f,0.f,0.f}, acc1 = (f32x4){0.f,0.f,0.f,0.f};

  // 2-deep named-slot pipeline: slot = 3 segs x 2 f32x4
  f32x4 Xa0, Xa1, Xb0, Xb1, Xc0, Xc1;   // slot 0
  f32x4 Ya0, Ya1, Yb0, Yb1, Yc0, Yc1;   // slot 1

#define LOADX(blk) do { const float* _o = p0 + (blk) * BK;                        \
    Xa0 = *(const f32x4*)(_o); Xa1 = *(const f32x4*)(_o + 4);                     \
    if (ok1) { const float* _p = p1 + (blk) * BK;                                 \
      Xb0 = *(const f32x4*)(_p); Xb1 = *(const f32x4*)(_p + 4);                   \
    } else { Xb0 = (f32x4){0.f,0.f,0.f,0.f}; Xb1 = Xb0; }                         \
    if (ok2) { const float* _q = p2 + (blk) * BK;                                 \
      Xc0 = *(const f32x4*)(_q); Xc1 = *(const f32x4*)(_q + 4);                   \
    } else { Xc0 = (f32x4){0.f,0.f,0.f,0.f}; Xc1 = Xc0; } } while (0)

#define LOADY(blk) do { const float* _o = p0 + (blk) * BK;                        \
    Ya0 = *(const f32x4*)(_o); Ya1 = *(const f32x4*)(_o + 4);                     \
    if (ok1) { const float* _p = p1 + (blk) * BK;                                 \
      Yb0 = *(const f32x4*)(_p); Yb1 = *(const f32x4*)(_p + 4);                   \
    } else { Yb0 = (f32x4){0.f,0.f,0.f,0.f}; Yb1 = Yb0; }                         \
    if (ok2) { const float* _q = p2 + (blk) * BK;                                 \
      Yc0 = *(const f32x4*)(_q); Yc1 = *(const f32x4*)(_q + 4);                   \
    } else { Yc0 = (f32x4){0.f,0.f,0.f,0.f}; Yc1 = Yc0; } } while (0)

#define WLDSX(buf) do { unsigned short* _d = lbase + (buf) * BUFE;                \
    cvt_store(_d,            Xa0, Xa1, n0);                                       \
    cvt_store(_d + SEGE,     Xb0, Xb1, n1);                                       \
    cvt_store(_d + 2 * SEGE, Xc0, Xc1, n2); } while (0)

#define WLDSY(buf) do { unsigned short* _d = lbase + (buf) * BUFE;                \
    cvt_store(_d,            Ya0, Ya1, n0);                                       \
    cvt_store(_d + SEGE,     Yb0, Yb1, n1);                                       \
    cvt_store(_d + 2 * SEGE, Yc0, Yc1, n2); } while (0)

  auto mstep = [&](int buf) {
    const unsigned short* pa = &T[buf][mrow + l15][g4 * 8];
    short8 af0 = *(const short8*)(pa);
    short8 af1 = *(const short8*)(pa + 32);
    const unsigned short* pb0 = &T[buf][TI + ncol + l15][g4 * 8];
    const unsigned short* pb1 = &T[buf][TI + ncol + 16 + l15][g4 * 8];
    short8 b00 = *(const short8*)(pb0);
    short8 b01 = *(const short8*)(pb0 + 32);
    short8 b10 = *(const short8*)(pb1);
    short8 b11 = *(const short8*)(pb1 + 32);
    acc0 = __builtin_amdgcn_mfma_f32_16x16x32_bf16(af0, b00, acc0, 0, 0, 0);
    acc0 = __builtin_amdgcn_mfma_f32_16x16x32_bf16(af1, b01, acc0, 0, 0, 0);
    acc1 = __builtin_amdgcn_mfma_f32_16x16x32_bf16(af0, b10, acc1, 0, 0, 0);
    acc1 = __builtin_amdgcn_mfma_f32_16x16x32_bf16(af1, b11, acc1, 0, 0, 0);
  };

  // ---- prologue ----
  LOADX(0);
  WLDSX(0);
  LOADY(1);
  __syncthreads();                     // buf0 (chunk0) ready

  // ---- main: 2 chunks/iter, loads issued one full phase before their WLDS ----
  #pragma unroll
  for (int it = 0; it < 7; ++it) {
    LOADX(2 * it + 2);
    mstep(0);                          // chunk 2it
    WLDSY(1);                          // chunk 2it+1 -> buf1
    __syncthreads();
    LOADY(2 * it + 3);
    mstep(1);                          // chunk 2it+1
    WLDSX(0);                          // chunk 2it+2 -> buf0
    __syncthreads();
  }
  mstep(0);                            // chunk 14
  WLDSY(1);                            // chunk 15 -> buf1
  __syncthreads();
  mstep(1);                            // chunk 15

  // ---- norms: reduce within 8-lane col groups, lane (t&7)==0 writes inv ----
  #pragma unroll
  for (int mm = 1; mm <= 4; mm <<= 1) {
    n0 += __shfl_xor(n0, mm, 64);
    n1 += __shfl_xor(n1, mm, 64);
    n2 += __shfl_xor(n2, mm, 64);
  }
  if ((t & 7) == 0) {
    invA[srow]      = 1.f / fmaxf(sqrtf(n0), 1e-8f);
    invB[srow]      = 1.f / fmaxf(sqrtf(n1), 1e-8f);
    invB[32 + srow] = 1.f / fmaxf(sqrtf(n2), 1e-8f);
  }
  __syncthreads();

  // ---- epilogue: weight, normalize (x2 side), reduce over 64 cols ----
  float rs[4];
  #pragma unroll
  for (int q = 0; q < 4; ++q) {
    const int il = mrow + g4 * 4 + q;            // local i
    const int j0l = ncol + l15;                  // acc0 col
    const int j1l = ncol + 16 + l15;             // acc1 col
    float w0 = __expf(-DECAY_F * fabsf((float)(il + 16 - j0l)));
    float w1 = __expf(-DECAY_F * fabsf((float)(il + 16 - j1l)));
    rs[q] = w0 * invB[j0l] * acc0[q] + w1 * invB[j1l] * acc1[q];
  }
  #pragma unroll
  for (int mm = 1; mm <= 8; mm <<= 1) {
    #pragma unroll
    for (int q = 0; q < 4; ++q) rs[q] += __shfl_xor(rs[q], mm, 64);
  }
  if (l15 == 0) {
    #pragma unroll
    for (int q = 0; q < 4; ++q) outAcc[mrow + g4 * 4 + q][wave & 1] = rs[q];
  }
  __syncthreads();

  if (t < TI) {
    const int gi   = i0 + t;
    const float A  = __expf(-DECAY_F);
    const float a1 = __expf(-DECAY_F * (float)(gi + 1));
    const float a2 = __expf(-DECAY_F * (float)(LSEQ - gi));
    const float Wi = (1.f - a1 + A - a2) / (1.f - A);   // exact sum_j a^|i-j|
    out[(size_t)b * LSEQ + gi] = Wi - invA[t] * (outAcc[t][0] + outAcc[t][1]);
  }
}

extern "C" void kernel_launch(void* const* d_in, const int* in_sizes, int n_in,
                              void* d_out, int out_size, void* d_ws, size_t ws_size,
                              hipStream_t stream) {
  const float* x1 = (const float*)d_in[0];
  const float* x2 = (const float*)d_in[1];
  float* out = (float*)d_out;
  dim3 grid(8 * (LSEQ / TI));   // 512 WGs = 2 per CU
  dim3 block(256);
  tsp_energy_kernel<<<grid, block, 0, stream>>>(x1, x2, out);
}

// Round 8
// 44.503 us; speedup vs baseline: 1.5220x; 1.4699x over previous
//
#include <hip/hip_runtime.h>

#define LSEQ   2048
#define DDIM   1024
#define TI     64           // output rows per WG
#define HALO   16           // a^17/(1-a) ~ 2e-6 truncation, invisible vs bf16 noise
#define TJ     (TI + 2*HALO)   // 96 x2 window rows
#define BK     64
#define NCH    (DDIM / BK)  // 16
#define LDST   72           // 64 + 8 pad bf16 elems -> 144B row stride (R0-proven)
#define DECAY_F 0.8f

typedef __attribute__((ext_vector_type(8))) short  short8;
typedef __attribute__((ext_vector_type(4))) short  short4v;
typedef __attribute__((ext_vector_type(4))) float  f32x4;

__device__ __forceinline__ unsigned short f2bf(float f) {
  unsigned u = __float_as_uint(f);
  u += 0x7fffu + ((u >> 16) & 1u);
  return (unsigned short)(u >> 16);
}

__device__ __forceinline__ void cvt_store8(unsigned short* dst, f32x4 lo, f32x4 hi, float& nsq) {
  short8 v;
  #pragma unroll
  for (int j = 0; j < 4; ++j) { float x = lo[j]; nsq += x * x; v[j]     = (short)f2bf(x); }
  #pragma unroll
  for (int j = 0; j < 4; ++j) { float x = hi[j]; nsq += x * x; v[4 + j] = (short)f2bf(x); }
  *(short8*)dst = v;
}

__device__ __forceinline__ void cvt_store4(unsigned short* dst, f32x4 lo, float& nsq) {
  short4v v;
  #pragma unroll
  for (int j = 0; j < 4; ++j) { float x = lo[j]; nsq += x * x; v[j] = (short)f2bf(x); }
  *(short4v*)dst = v;
}

__global__ __launch_bounds__(512, 1)
void tsp_energy_kernel(const float* __restrict__ x1,
                       const float* __restrict__ x2,
                       float* __restrict__ out) {
  // XCD pinning: round-robin dispatch -> bid&7 = XCD. XCD x owns ALL 32 tiles
  // of batch x simultaneously (1 WG/CU, 32 CU/XCD) -> every halo row re-read
  // is same-XCD L2-resident. Cuts fabric traffic toward the 134 MB floor.
  const int bid = blockIdx.x;
  const int b   = bid & 7;
  const int i0  = (bid >> 3) * TI;

  const int t    = threadIdx.x;
  const int lane = t & 63;
  const int wave = t >> 6;            // 8 waves: mrow = (w>>1)*16, ncol = (w&1)*48
  const int l15  = lane & 15;
  const int g4   = lane >> 4;
  const int mrow = (wave >> 1) * 16;
  const int ncol = (wave & 1) * 48;

  __shared__ unsigned short Al[2][TI][LDST];
  __shared__ unsigned short Bl[2][TJ][LDST];
  __shared__ float nsq1p[512], nsq2p[512], nsq3p[512];
  __shared__ float inv1[TI], inv2[TJ];
  __shared__ float outAcc[TI][2];

  // staging: A 64x64/chunk (8 f/thread), B seg1 64 rows (8 f), seg2 32 rows (4 f)
  const int arow = t >> 3;            // 0..63
  const int ac0  = (t & 7) * 8;
  const int crow = t >> 4;            // 0..31 (seg2)
  const int cc0  = (t & 15) * 4;
  const int j1   = i0 - HALO + arow;          // seg1 global x2 row (window rows 0..63)
  const int j2   = i0 + 48 + crow;            // seg2 global x2 row (window rows 64..95)
  const bool ok1 = (j1 >= 0);                 // j1 <= 2031 always
  const bool ok2 = (j2 < LSEQ);               // j2 >= 48 always

  const float* ap  = x1 + ((size_t)b * LSEQ + i0 + arow) * DDIM + ac0;
  const float* bp1 = x2 + ((size_t)b * LSEQ + (ok1 ? j1 : 0)) * DDIM + ac0;
  const float* bp2 = x2 + ((size_t)b * LSEQ + (ok2 ? j2 : 0)) * DDIM + cc0;

  float nsqa = 0.f, nsqb1 = 0.f, nsqb2 = 0.f;
  f32x4 acc[3];
  #pragma unroll
  for (int n = 0; n < 3; ++n) acc[n] = (f32x4){0.f, 0.f, 0.f, 0.f};

  // 2-deep named-slot pipeline: slot = 5 x f32x4 (A:2, Bseg1:2, Bseg2:1)
  f32x4 Xa0, Xa1, Xb0, Xb1, Xc0;
  f32x4 Ya0, Ya1, Yb0, Yb1, Yc0;

#define LOADX(blk) do {                                                           \
    Xa0 = *(const f32x4*)(ap + (blk) * BK); Xa1 = *(const f32x4*)(ap + (blk) * BK + 4); \
    if (ok1) { Xb0 = *(const f32x4*)(bp1 + (blk) * BK); Xb1 = *(const f32x4*)(bp1 + (blk) * BK + 4); } \
    else     { Xb0 = (f32x4){0.f,0.f,0.f,0.f}; Xb1 = Xb0; }                       \
    if (ok2) { Xc0 = *(const f32x4*)(bp2 + (blk) * BK); }                         \
    else     { Xc0 = (f32x4){0.f,0.f,0.f,0.f}; } } while (0)

#define LOADY(blk) do {                                                           \
    Ya0 = *(const f32x4*)(ap + (blk) * BK); Ya1 = *(const f32x4*)(ap + (blk) * BK + 4); \
    if (ok1) { Yb0 = *(const f32x4*)(bp1 + (blk) * BK); Yb1 = *(const f32x4*)(bp1 + (blk) * BK + 4); } \
    else     { Yb0 = (f32x4){0.f,0.f,0.f,0.f}; Yb1 = Yb0; }                       \
    if (ok2) { Yc0 = *(const f32x4*)(bp2 + (blk) * BK); }                         \
    else     { Yc0 = (f32x4){0.f,0.f,0.f,0.f}; } } while (0)

#define WLDSX(buf) do {                                                           \
    cvt_store8(&Al[buf][arow][ac0],      Xa0, Xa1, nsqa);                         \
    cvt_store8(&Bl[buf][arow][ac0],      Xb0, Xb1, nsqb1);                        \
    cvt_store4(&Bl[buf][64 + crow][cc0], Xc0, nsqb2); } while (0)

#define WLDSY(buf) do {                                                           \
    cvt_store8(&Al[buf][arow][ac0],      Ya0, Ya1, nsqa);                         \
    cvt_store8(&Bl[buf][arow][ac0],      Yb0, Yb1, nsqb1);                        \
    cvt_store4(&Bl[buf][64 + crow][cc0], Yc0, nsqb2); } while (0)

  auto mstep = [&](int buf) {
    const unsigned short* pa = &Al[buf][mrow + l15][g4 * 8];
    short8 af0 = *(const short8*)(pa);
    short8 af1 = *(const short8*)(pa + 32);
    #pragma unroll
    for (int n = 0; n < 3; ++n) {
      const unsigned short* pb = &Bl[buf][ncol + n * 16 + l15][g4 * 8];
      short8 bf0 = *(const short8*)(pb);
      short8 bf1 = *(const short8*)(pb + 32);
      acc[n] = __builtin_amdgcn_mfma_f32_16x16x32_bf16(af0, bf0, acc[n], 0, 0, 0);
      acc[n] = __builtin_amdgcn_mfma_f32_16x16x32_bf16(af1, bf1, acc[n], 0, 0, 0);
    }
  };

  // ---- prologue: chunk0 -> buf0, chunk1 in regs ----
  LOADX(0);
  WLDSX(0);
  LOADY(1);
  __syncthreads();                     // buf0 ready

  // ---- main: 2 chunks/iter, loads issued one full phase ahead of their WLDS ----
  #pragma unroll
  for (int it = 0; it < 7; ++it) {
    LOADX(2 * it + 2);
    mstep(0);                          // chunk 2it
    WLDSY(1);                          // chunk 2it+1 -> buf1
    __syncthreads();
    LOADY(2 * it + 3);
    mstep(1);                          // chunk 2it+1
    WLDSX(0);                          // chunk 2it+2 -> buf0
    __syncthreads();
  }
  mstep(0);                            // chunk 14
  WLDSY(1);                            // chunk 15 -> buf1
  __syncthreads();
  mstep(1);                            // chunk 15

  // ---- norms (fp32 partials accumulated during cvt) ----
  nsq1p[t] = nsqa;
  nsq2p[t] = nsqb1;
  nsq3p[t] = nsqb2;
  __syncthreads();
  if (t < 64) {
    float s = 0.f;
    #pragma unroll
    for (int k = 0; k < 8; ++k) s += nsq1p[t * 8 + k];
    inv1[t] = 1.f / fmaxf(sqrtf(s), 1e-8f);
  } else if (t < 128) {
    const int r = t - 64;
    float s = 0.f;
    #pragma unroll
    for (int k = 0; k < 8; ++k) s += nsq2p[r * 8 + k];
    inv2[r] = 1.f / fmaxf(sqrtf(s), 1e-8f);
  } else if (t < 160) {
    const int r = t - 128;
    float s = 0.f;
    #pragma unroll
    for (int k = 0; k < 16; ++k) s += nsq3p[r * 16 + k];
    inv2[64 + r] = 1.f / fmaxf(sqrtf(s), 1e-8f);
  }
  __syncthreads();

  // ---- epilogue: weight, normalize (x2 side), reduce over wave's 48 cols ----
  float rs[4] = {0.f, 0.f, 0.f, 0.f};
  #pragma unroll
  for (int n = 0; n < 3; ++n) {
    const int jloc = ncol + n * 16 + l15;        // window col 0..95
    const float iv2 = inv2[jloc];
    #pragma unroll
    for (int q = 0; q < 4; ++q) {
      const int irel = mrow + g4 * 4 + q;        // local out row
      const float d = fabsf((float)(jloc - HALO - irel));
      rs[q] += __expf(-DECAY_F * d) * iv2 * acc[n][q];
    }
  }
  #pragma unroll
  for (int mm = 1; mm <= 8; mm <<= 1) {
    #pragma unroll
    for (int q = 0; q < 4; ++q) rs[q] += __shfl_xor(rs[q], mm, 64);
  }
  if (l15 == 0) {
    #pragma unroll
    for (int q = 0; q < 4; ++q) outAcc[mrow + g4 * 4 + q][wave & 1] = rs[q];
  }
  __syncthreads();

  if (t < TI) {
    const int gi   = i0 + t;
    const float A  = __expf(-DECAY_F);
    const float a1 = __expf(-DECAY_F * (float)(gi + 1));
    const float a2 = __expf(-DECAY_F * (float)(LSEQ - gi));
    const float Wi = (1.f - a1 + A - a2) / (1.f - A);   // exact sum_j a^|i-j|
    out[(size_t)b * LSEQ + gi] = Wi - inv1[t] * (outAcc[t][0] + outAcc[t][1]);
  }
}

extern "C" void kernel_launch(void* const* d_in, const int* in_sizes, int n_in,
                              void* d_out, int out_size, void* d_ws, size_t ws_size,
                              hipStream_t stream) {
  const float* x1 = (const float*)d_in[0];
  const float* x2 = (const float*)d_in[1];
  float* out = (float*)d_out;
  dim3 grid(8 * (LSEQ / TI));   // 256 WGs = 1 per CU, XCD-pinned by bid&7
  dim3 block(512);
  tsp_energy_kernel<<<grid, block, 0, stream>>>(x1, x2, out);
}

// Round 9
// 29.074 us; speedup vs baseline: 2.3297x; 1.5307x over previous
//
#include <hip/hip_runtime.h>

#define LSEQ   2048
#define DDIM   1024
#define TI     64           // output rows per WG
#define HALO   8            // trunc err ~ 2*a^9/(1-a)*|sim| ~ 4e-4, invisible
#define TJ     (TI + 2*HALO)   // 80 x2 window rows
#define BK     64
#define NCH    (DDIM / BK)  // 16
#define LDST   72           // 64 + 8 pad bf16 elems -> 144B row stride (R0-proven)
#define DECAY_F 0.8f

typedef __attribute__((ext_vector_type(8))) short  short8;
typedef __attribute__((ext_vector_type(4))) float  f32x4;

__device__ __forceinline__ unsigned short f2bf(float f) {
  unsigned u = __float_as_uint(f);
  u += 0x7fffu + ((u >> 16) & 1u);
  return (unsigned short)(u >> 16);
}

__device__ __forceinline__ void cvt_store8(unsigned short* dst, f32x4 lo, f32x4 hi, float& nsq) {
  short8 v;
  #pragma unroll
  for (int j = 0; j < 4; ++j) { float x = lo[j]; nsq += x * x; v[j]     = (short)f2bf(x); }
  #pragma unroll
  for (int j = 0; j < 4; ++j) { float x = hi[j]; nsq += x * x; v[4 + j] = (short)f2bf(x); }
  *(short8*)dst = v;
}

__global__ __launch_bounds__(512, 1)
void tsp_energy_kernel(const float* __restrict__ x1,
                       const float* __restrict__ x2,
                       float* __restrict__ out) {
  // XCD pinning: round-robin dispatch -> bid&7 = XCD = batch. All 32 tiles of a
  // batch co-resident on one XCD; per-chunk working set ~1.2 MB < 4 MB L2, so
  // halo re-reads L2-hit. R0 structure otherwise (52 VGPR, proven no-spill).
  const int bid = blockIdx.x;
  const int b   = bid & 7;
  const int i0  = (bid >> 3) * TI;

  const int t    = threadIdx.x;
  const int lane = t & 63;
  const int wave = t >> 6;            // 8 waves
  const int l15  = lane & 15;
  const int g4   = lane >> 4;
  const int mrow = (wave & 3) * 16;   // output row block
  const int wh   = wave >> 2;         // column-set selector: cols {wh+2k}
  // wave w<4: B-cols {0,2,4}*16; w>=4: {1,3}*16 (col 5 doesn't exist)

  __shared__ unsigned short Al[2][TI][LDST];
  __shared__ unsigned short Bl[2][TJ][LDST];
  __shared__ float nsq1p[512], nsq2p[512], nsq3p[128];
  __shared__ float inv1[TI], inv2[TJ];
  __shared__ float outAcc[TI][2];

  // staging: A + B1 use rows 0..63 (8 threads/row, 8 f each); B2 rows 64..79
  // staged by threads 0..127 only.
  const int arow = t >> 3;                 // 0..63
  const int ac0  = (t & 7) * 8;
  const int j1   = i0 - HALO + arow;       // window row arow (j1 < 2048 always)
  const bool ok1 = (j1 >= 0);
  const bool hasB2 = (t < 128);            // arow 0..15 doubles as B2 row idx
  const int j2   = i0 + (TI - HALO) + arow;   // window row 64+arow
  const bool ok2 = hasB2 && (j2 < LSEQ);

  const float* ap  = x1 + ((size_t)b * LSEQ + i0 + arow) * DDIM + ac0;
  const float* bp1 = x2 + ((size_t)b * LSEQ + (ok1 ? j1 : 0)) * DDIM + ac0;
  const float* bp2 = x2 + ((size_t)b * LSEQ + (ok2 ? j2 : 0)) * DDIM + ac0;

  float nsqa = 0.f, nsqb1 = 0.f, nsqb2 = 0.f;
  f32x4 acc0 = (f32x4){0.f,0.f,0.f,0.f};
  f32x4 acc1 = (f32x4){0.f,0.f,0.f,0.f};
  f32x4 acc2 = (f32x4){0.f,0.f,0.f,0.f};

  // single-slot reg staging (R0-proven): loaded at top of iter, stored at bottom
  f32x4 Va0, Va1, Vb0, Vb1, Vc0, Vc1;

  auto load_regs = [&](int c) {
    const float* pA = ap + c * BK;
    Va0 = *(const f32x4*)(pA); Va1 = *(const f32x4*)(pA + 4);
    if (ok1) { const float* p = bp1 + c * BK; Vb0 = *(const f32x4*)(p); Vb1 = *(const f32x4*)(p + 4); }
    else     { Vb0 = (f32x4){0.f,0.f,0.f,0.f}; Vb1 = Vb0; }
    if (ok2) { const float* p = bp2 + c * BK; Vc0 = *(const f32x4*)(p); Vc1 = *(const f32x4*)(p + 4); }
    else     { Vc0 = (f32x4){0.f,0.f,0.f,0.f}; Vc1 = Vc0; }
  };

  auto write_lds = [&](int buf) {
    cvt_store8(&Al[buf][arow][ac0], Va0, Va1, nsqa);
    cvt_store8(&Bl[buf][arow][ac0], Vb0, Vb1, nsqb1);
    if (hasB2) cvt_store8(&Bl[buf][TI + arow][ac0], Vc0, Vc1, nsqb2);
  };

  auto mstep = [&](int buf) {
    const unsigned short* pa = &Al[buf][mrow + l15][g4 * 8];
    short8 af0 = *(const short8*)(pa);
    short8 af1 = *(const short8*)(pa + 32);
    {
      const unsigned short* pb = &Bl[buf][(wh + 0) * 16 + l15][g4 * 8];
      short8 b0 = *(const short8*)(pb), b1 = *(const short8*)(pb + 32);
      acc0 = __builtin_amdgcn_mfma_f32_16x16x32_bf16(af0, b0, acc0, 0, 0, 0);
      acc0 = __builtin_amdgcn_mfma_f32_16x16x32_bf16(af1, b1, acc0, 0, 0, 0);
    }
    {
      const unsigned short* pb = &Bl[buf][(wh + 2) * 16 + l15][g4 * 8];
      short8 b0 = *(const short8*)(pb), b1 = *(const short8*)(pb + 32);
      acc1 = __builtin_amdgcn_mfma_f32_16x16x32_bf16(af0, b0, acc1, 0, 0, 0);
      acc1 = __builtin_amdgcn_mfma_f32_16x16x32_bf16(af1, b1, acc1, 0, 0, 0);
    }
    if (wh == 0) {
      const unsigned short* pb = &Bl[buf][4 * 16 + l15][g4 * 8];
      short8 b0 = *(const short8*)(pb), b1 = *(const short8*)(pb + 32);
      acc2 = __builtin_amdgcn_mfma_f32_16x16x32_bf16(af0, b0, acc2, 0, 0, 0);
      acc2 = __builtin_amdgcn_mfma_f32_16x16x32_bf16(af1, b1, acc2, 0, 0, 0);
    }
  };

  // ---- main K-loop: R0-proven schedule ----
  load_regs(0);
  write_lds(0);
  for (int c = 0; c < NCH; ++c) {
    if (c + 1 < NCH) load_regs(c + 1);   // issue next-chunk loads early
    __syncthreads();                     // buf[c&1] writes visible
    mstep(c & 1);
    if (c + 1 < NCH) write_lds((c + 1) & 1);
  }

  // ---- norms (fp32 partials accumulated during cvt) ----
  nsq1p[t] = nsqa;
  nsq2p[t] = nsqb1;
  if (hasB2) nsq3p[t] = nsqb2;
  __syncthreads();
  if (t < TI) {
    float s = 0.f;
    #pragma unroll
    for (int k = 0; k < 8; ++k) s += nsq1p[t * 8 + k];
    inv1[t] = 1.f / fmaxf(sqrtf(s), 1e-8f);
  } else if (t < 2 * TI) {
    const int r = t - TI;
    float s = 0.f;
    #pragma unroll
    for (int k = 0; k < 8; ++k) s += nsq2p[r * 8 + k];
    inv2[r] = 1.f / fmaxf(sqrtf(s), 1e-8f);
  } else if (t < 2 * TI + 16) {
    const int r = t - 2 * TI;            // 0..15
    float s = 0.f;
    #pragma unroll
    for (int k = 0; k < 8; ++k) s += nsq3p[r * 8 + k];
    inv2[TI + r] = 1.f / fmaxf(sqrtf(s), 1e-8f);
  }
  __syncthreads();

  // ---- epilogue: weight, normalize (x2 side), reduce over wave's cols ----
  float rs[4];
  {
    const int jw0 = (wh + 0) * 16 + l15;
    const int jw1 = (wh + 2) * 16 + l15;
    const int jw2 = 4 * 16 + l15;
    const float iv0 = inv2[jw0];
    const float iv1 = inv2[jw1];
    const float iv2v = (wh == 0) ? inv2[jw2] : 0.f;
    #pragma unroll
    for (int q = 0; q < 4; ++q) {
      const int ir = mrow + g4 * 4 + q;            // local out row
      float s = __expf(-DECAY_F * fabsf((float)(jw0 - HALO - ir))) * iv0 * acc0[q]
              + __expf(-DECAY_F * fabsf((float)(jw1 - HALO - ir))) * iv1 * acc1[q];
      if (wh == 0)
        s += __expf(-DECAY_F * fabsf((float)(jw2 - HALO - ir))) * iv2v * acc2[q];
      rs[q] = s;
    }
  }
  #pragma unroll
  for (int mm = 1; mm <= 8; mm <<= 1) {
    #pragma unroll
    for (int q = 0; q < 4; ++q) rs[q] += __shfl_xor(rs[q], mm, 64);
  }
  if (l15 == 0) {
    #pragma unroll
    for (int q = 0; q < 4; ++q) outAcc[mrow + g4 * 4 + q][wh] = rs[q];
  }
  __syncthreads();

  if (t < TI) {
    const int gi   = i0 + t;
    const float A  = __expf(-DECAY_F);
    const float a1 = __expf(-DECAY_F * (float)(gi + 1));
    const float a2 = __expf(-DECAY_F * (float)(LSEQ - gi));
    const float Wi = (1.f - a1 + A - a2) / (1.f - A);   // exact sum_j a^|i-j|
    out[(size_t)b * LSEQ + gi] = Wi - inv1[t] * (outAcc[t][0] + outAcc[t][1]);
  }
}

extern "C" void kernel_launch(void* const* d_in, const int* in_sizes, int n_in,
                              void* d_out, int out_size, void* d_ws, size_t ws_size,
                              hipStream_t stream) {
  const float* x1 = (const float*)d_in[0];
  const float* x2 = (const float*)d_in[1];
  float* out = (float*)d_out;
  dim3 grid(8 * (LSEQ / TI));   // 256 WGs = 1 per CU, XCD-pinned by bid&7
  dim3 block(512);
  tsp_energy_kernel<<<grid, block, 0, stream>>>(x1, x2, out);
}